// Round 2
// baseline (359.834 us; speedup 1.0000x reference)
//
#include <hip/hip_runtime.h>
#include <hip/hip_bf16.h>
#include <math.h>

// Problem constants
#define CDIM 256
#define HW   1024          // 32*32
#define NVEC 32768         // B*H*W
#define NE   1024
#define ZSIZE 8388608      // 32*256*32*32
#define NSPLIT 2           // j-splits (512 codes each)
#define MARGIN 0.05f       // 3-term split-bf16 score error sigma ~1e-4 -> 500 sigma

// Output layout (floats): [loss(1)][z_q(ZSIZE)][perp(1)][idx(NVEC)][z_q1(ZSIZE)]
#define OUT_LOSS 0
#define OUT_ZQ   1
#define OUT_PERP 8388609
#define OUT_IDX  8388610
#define OUT_ZQ1  8421378

// Workspace layout (bytes)
#define WS_LOSS   0
#define WS_RCNT   64
#define WS_HIST   128       // 1024 ints  -> 4224
#define WS_ENORM  4224      // 1024 floats -> 8320
#define WS_IDX    8448      // 32768 ints -> 139520
#define WS_RLIST  139520    // 32768 ints -> 270592
#define WS_S1     270592    // 2*32768 f  -> 532736
#define WS_S2     532736    // -> 794880
#define WS_J1     794880    // -> 1057024
#define WS_EBH    1057024   // 1024*256 bf16 -> 1581312
#define WS_EBL    1581312   // -> 2105600
#define WS_ZBH    2105600   // 32768*256 bf16 -> 18882816
#define WS_ZBL    18882816  // -> 35660032

typedef __attribute__((ext_vector_type(8))) short short8;
typedef __attribute__((ext_vector_type(4))) float f32x4;
typedef __attribute__((ext_vector_type(8))) unsigned short ushort8v;

__device__ __forceinline__ unsigned short bf16_rne(float x) {
    union { float f; unsigned u; } v; v.f = x;
    unsigned r = v.u + 0x7FFFu + ((v.u >> 16) & 1u);
    return (unsigned short)(r >> 16);
}
__device__ __forceinline__ float bf16_to_f(unsigned short h) {
    union { unsigned u; float f; } v; v.u = ((unsigned)h) << 16;
    return v.f;
}
// CK-style block_sync_lds: drains LDS ops + barrier, leaves global loads (vmcnt) in flight.
__device__ __forceinline__ void lds_barrier() {
    asm volatile("s_waitcnt lgkmcnt(0)\n\ts_barrier" ::: "memory");
}

// ---------------- fused prep: z transpose+split (blocks 0..511), emb split+norm (512..527)
__global__ __launch_bounds__(256) void vq_prep(
    const float* __restrict__ z, const float* __restrict__ emb,
    unsigned short* __restrict__ zbh, unsigned short* __restrict__ zbl,
    unsigned short* __restrict__ ebh, unsigned short* __restrict__ ebl,
    float* __restrict__ enorm)
{
    const int tid = threadIdx.x, w = tid >> 6, L = tid & 63;
    if (blockIdx.x < 512) {
        __shared__ unsigned short th[64 * 264];
        __shared__ unsigned short tl[64 * 264];
        const int b = blockIdx.x >> 4, hw0 = (blockIdx.x & 15) << 6;
        const float* zp = z + (size_t)b * (CDIM * HW) + hw0;
        for (int i = 0; i < 16; ++i) {
            int k = (i * 4 + w) * 4;
            float f0 = zp[(size_t)(k + 0) * HW + L];
            float f1 = zp[(size_t)(k + 1) * HW + L];
            float f2 = zp[(size_t)(k + 2) * HW + L];
            float f3 = zp[(size_t)(k + 3) * HW + L];
            ushort4 hi = { bf16_rne(f0), bf16_rne(f1), bf16_rne(f2), bf16_rne(f3) };
            ushort4 lo = { bf16_rne(f0 - bf16_to_f(hi.x)), bf16_rne(f1 - bf16_to_f(hi.y)),
                           bf16_rne(f2 - bf16_to_f(hi.z)), bf16_rne(f3 - bf16_to_f(hi.w)) };
            *(ushort4*)&th[L * 264 + k] = hi;
            *(ushort4*)&tl[L * 264 + k] = lo;
        }
        __syncthreads();
#pragma unroll
        for (int it = 0; it < 8; ++it) {
            int row = it * 8 + (tid >> 5);
            int kc = (tid & 31) * 8;
            size_t o = (size_t)(b * 1024 + hw0 + row) * CDIM + kc;
            *(ushort8v*)(zbh + o) = *(ushort8v*)&th[row * 264 + kc];
            *(ushort8v*)(zbl + o) = *(ushort8v*)&tl[row * 264 + kc];
        }
    } else {
        const int cb = (int)(blockIdx.x - 512) * 64;
        for (int p = 0; p < 16; ++p) {
            int code = cb + p * 4 + w;
            float4 v = *(const float4*)(emb + (size_t)code * CDIM + L * 4);
            float s = v.x * v.x + v.y * v.y + v.z * v.z + v.w * v.w;
            for (int off = 32; off; off >>= 1) s += __shfl_down(s, off, 64);
            if (L == 0) enorm[code] = s;
            ushort4 hi = { bf16_rne(v.x), bf16_rne(v.y), bf16_rne(v.z), bf16_rne(v.w) };
            ushort4 lo = { bf16_rne(v.x - bf16_to_f(hi.x)), bf16_rne(v.y - bf16_to_f(hi.y)),
                           bf16_rne(v.z - bf16_to_f(hi.z)), bf16_rne(v.w - bf16_to_f(hi.w)) };
            *(ushort4*)(ebh + (size_t)code * CDIM + L * 4) = hi;
            *(ushort4*)(ebl + (size_t)code * CDIM + L * 4) = lo;
        }
    }
}

// ---------------- 3-term split-bf16 MFMA GEMM, LDS-staged, j-loop inside ----------
__global__ __launch_bounds__(256, 2) void vq_mfma3(
    const unsigned short* __restrict__ zbh, const unsigned short* __restrict__ zbl,
    const unsigned short* __restrict__ ebh, const unsigned short* __restrict__ ebl,
    const float* __restrict__ enorm,
    float* __restrict__ s1_ws, float* __restrict__ s2_ws, int* __restrict__ j1_ws)
{
    __shared__ short albuf[32768];   // 64KB: AL frags, seg(w,mf,kk)=w*16+mf*8+kk, 512 shorts/seg
    __shared__ short bbuf[8192];     // 16KB: B frags, hi: seg=jf, lo: seg=8+jf

    const int tid = threadIdx.x, w = tid >> 6, L = tid & 63;
    const int l15 = L & 15, q = L >> 4;
    const int r16 = tid & 15, ch = (tid >> 4) & 3;
    const int mtile = blockIdx.x & 255, js = blockIdx.x >> 8;
    const int n0 = mtile << 7;
    const int jsbase = js << 9;

    // stage AL (fragment order)
#pragma unroll
    for (int ro = 0; ro < 16; ++ro) {
        const int seg = ro * 4 + w;
        const int sw2 = seg >> 4, smf = (seg >> 3) & 1, skk = seg & 7;
        short8 v = *(const short8*)(zbl + (size_t)(n0 + sw2 * 32 + smf * 16 + r16) * CDIM + skk * 32 + ch * 8);
        *(short8*)(albuf + seg * 512 + L * 8) = v;
    }
    short8 AH[2][8];
#pragma unroll
    for (int mf = 0; mf < 2; ++mf)
#pragma unroll
        for (int kk = 0; kk < 8; ++kk)
            AH[mf][kk] = *(const short8*)(zbh + (size_t)(n0 + w * 32 + mf * 16 + l15) * CDIM + kk * 32 + q * 8);
    __syncthreads();

    float s1[2][4], s2[2][4]; int j1[2][4];
#pragma unroll
    for (int mf = 0; mf < 2; ++mf)
#pragma unroll
        for (int r = 0; r < 4; ++r) { s1[mf][r] = -3.4e38f; s2[mf][r] = -3.4e38f; j1[mf][r] = 0; }

    for (int j0i = 0; j0i < 4; ++j0i) {
        const int j0 = jsbase + j0i * 128;
        f32x4 acc[2][8] = {};
        short8 st[4];
#pragma unroll
        for (int ro = 0; ro < 4; ++ro) {
            const unsigned short* src = (ro >= 2) ? ebl : ebh;
            const int jf = (ro & 1) * 4 + w;
            st[ro] = *(const short8*)(src + (size_t)(j0 + jf * 16 + r16) * CDIM + ch * 8);
        }
#pragma unroll
        for (int kk = 0; kk < 8; ++kk) {
            lds_barrier();
#pragma unroll
            for (int ro = 0; ro < 4; ++ro)
                *(short8*)(bbuf + (ro * 4 + w) * 512 + L * 8) = st[ro];
            if (kk < 7) {
                const int k0n = (kk + 1) * 32;
#pragma unroll
                for (int ro = 0; ro < 4; ++ro) {
                    const unsigned short* src = (ro >= 2) ? ebl : ebh;
                    const int jf = (ro & 1) * 4 + w;
                    st[ro] = *(const short8*)(src + (size_t)(j0 + jf * 16 + r16) * CDIM + k0n + ch * 8);
                }
            }
            lds_barrier();
            short8 AL0 = *(const short8*)(albuf + (w * 16 + kk) * 512 + L * 8);
            short8 AL1 = *(const short8*)(albuf + (w * 16 + 8 + kk) * 512 + L * 8);
#pragma unroll
            for (int jf = 0; jf < 8; ++jf) {
                short8 Bh = *(const short8*)(bbuf + jf * 512 + L * 8);
                short8 Bl = *(const short8*)(bbuf + (8 + jf) * 512 + L * 8);
                acc[0][jf] = __builtin_amdgcn_mfma_f32_16x16x32_bf16(AH[0][kk], Bh, acc[0][jf], 0, 0, 0);
                acc[1][jf] = __builtin_amdgcn_mfma_f32_16x16x32_bf16(AH[1][kk], Bh, acc[1][jf], 0, 0, 0);
                acc[0][jf] = __builtin_amdgcn_mfma_f32_16x16x32_bf16(AH[0][kk], Bl, acc[0][jf], 0, 0, 0);
                acc[1][jf] = __builtin_amdgcn_mfma_f32_16x16x32_bf16(AH[1][kk], Bl, acc[1][jf], 0, 0, 0);
                acc[0][jf] = __builtin_amdgcn_mfma_f32_16x16x32_bf16(AL0, Bh, acc[0][jf], 0, 0, 0);
                acc[1][jf] = __builtin_amdgcn_mfma_f32_16x16x32_bf16(AL1, Bh, acc[1][jf], 0, 0, 0);
            }
        }
#pragma unroll
        for (int jf = 0; jf < 8; ++jf) {
            const int j = j0 + jf * 16 + l15;
            const float hn = 0.5f * enorm[j];
#pragma unroll
            for (int mf = 0; mf < 2; ++mf)
#pragma unroll
                for (int r = 0; r < 4; ++r) {
                    float s = acc[mf][jf][r] - hn;
                    if (s > s1[mf][r]) { s2[mf][r] = s1[mf][r]; s1[mf][r] = s; j1[mf][r] = j; }
                    else if (s > s2[mf][r]) s2[mf][r] = s;
                }
        }
    }

#pragma unroll
    for (int mf = 0; mf < 2; ++mf)
#pragma unroll
        for (int r = 0; r < 4; ++r) {
            float a1 = s1[mf][r], a2 = s2[mf][r]; int aj = j1[mf][r];
            for (int m = 1; m < 16; m <<= 1) {
                float o1 = __shfl_xor(a1, m, 64);
                float o2 = __shfl_xor(a2, m, 64);
                int   oj = __shfl_xor(aj, m, 64);
                if (o1 > a1 || (o1 == a1 && oj < aj)) { a2 = fmaxf(a1, o2); a1 = o1; aj = oj; }
                else a2 = fmaxf(a2, o1);
            }
            if (l15 == 0) {
                int o = js * NVEC + n0 + w * 32 + mf * 16 + q * 4 + r;
                s1_ws[o] = a1; s2_ws[o] = a2; j1_ws[o] = aj;
            }
        }
}

// ---------------- merge 2 splits; hist+idx_out for confident rows; flag rest ----
__global__ __launch_bounds__(256) void vq_merge(
    const float* __restrict__ s1_ws, const float* __restrict__ s2_ws,
    const int* __restrict__ j1_ws, int* __restrict__ idx_ws,
    float* __restrict__ idx_out, int* __restrict__ hist,
    int* __restrict__ rcnt, int* __restrict__ rlist)
{
    int n = blockIdx.x * 256 + threadIdx.x;
    float b1 = -3.4e38f, b2 = -3.4e38f; int bj = 0;
#pragma unroll
    for (int s = 0; s < NSPLIT; ++s) {
        float a1 = s1_ws[s * NVEC + n], a2 = s2_ws[s * NVEC + n];
        int aj = j1_ws[s * NVEC + n];
        if (a1 > b1 || (a1 == b1 && aj < bj)) { b2 = fmaxf(b1, a2); b1 = a1; bj = aj; }
        else b2 = fmaxf(b2, a1);
    }
    idx_ws[n] = bj;
    if (b1 - b2 < MARGIN) {
        int p = atomicAdd(rcnt, 1); rlist[p] = n;
    } else {
        idx_out[n] = (float)bj;
        atomicAdd(&hist[bj], 1);
    }
}

// ---------------- exact fp32 rescore of flagged rows ---------------------------
// Post-mortem r0/r1: count is only ~50-60 rows (FETCH ~ 8MB emb-per-XCD + ~16KB/row),
// so rescue duration == SINGLE-ROW serial latency (~69us from 6-deep shuffle chains
// with VGPR=24, zero loads in flight). v3: one block per row, emb streamed through
// double-buffered 64-code LDS tiles. Per pass: wave-coalesced loads (1 code row =
// 1KB = exactly one wave-load), padded LDS (272-word code stride, 68-word part
// stride -> conflict-free b128), thread owns (code, quarter): 16 ds_read_b128 +
// 64 FMA, then TWO shuffles per code (4-lane group sum). z slice in registers.
// Next tile's loads issue before compute; lds_barrier keeps vmcnt in flight.
__global__ __launch_bounds__(256) void vq_rescue(
    const float* __restrict__ z, const float* __restrict__ emb,
    const float* __restrict__ enorm, const int* __restrict__ rcnt,
    const int* __restrict__ rlist, int* __restrict__ idx_ws,
    float* __restrict__ idx_out, int* __restrict__ hist)
{
    // LDS: 2 x 64 codes x 272 words (code = 4 parts x 68 words) = 139264 B
    __shared__ __align__(16) float lds_e[2][64 * 272];
    __shared__ __align__(16) float zrowp[4 * 68];   // z row, 68-word part stride
    __shared__ float lds_en[NE];
    __shared__ float rs[4];
    __shared__ int   rj[4];

    const int tid = threadIdx.x;
    const int w = tid >> 6, L = tid & 63;
    const int c = tid >> 2, qp = tid & 3;           // compute: code-in-tile, quarter
    const int wr = (L >> 4) * 68 + (L & 15) * 4;    // stage: part/k word offset for lane
    const int count = *rcnt;

    // stage enorm once (first in-loop barrier makes it visible)
    for (int i = tid; i < NE; i += 256) lds_en[i] = enorm[i];

    for (int it = blockIdx.x; it < count; it += gridDim.x) {
        __syncthreads();   // protect LDS reuse across rows (and enorm on first row)
        const int n = rlist[it];

        // issue tile-0 loads + scattered z element
        float4 st[16];
#pragma unroll
        for (int i = 0; i < 16; ++i)
            st[i] = *(const float4*)(emb + (size_t)(i * 4 + w) * CDIM + L * 4);
        const float zval = z[(size_t)(n >> 10) * (CDIM * HW) + (size_t)tid * HW + (n & 1023)];

        // write z + tile0 into LDS (compiler inserts vmcnt waits per-register)
        zrowp[(tid >> 6) * 68 + (tid & 63)] = zval;
#pragma unroll
        for (int i = 0; i < 16; ++i)
            *(float4*)&lds_e[0][(i * 4 + w) * 272 + wr] = st[i];
        lds_barrier();

        // preload this thread's 64-dim z slice to registers
        float4 zr[16];
#pragma unroll
        for (int k = 0; k < 16; ++k)
            zr[k] = *(const float4*)&zrowp[qp * 68 + k * 4];

        float b1 = -3.4e38f; int bj = 0x7fffffff;
        const int cbase = c * 272 + qp * 68;

#pragma unroll 1
        for (int p = 0; p < 16; ++p) {
            // issue next tile's global loads (stay in flight across barriers)
            if (p < 15) {
                const int j0 = (p + 1) * 64;
#pragma unroll
                for (int i = 0; i < 16; ++i)
                    st[i] = *(const float4*)(emb + (size_t)(j0 + i * 4 + w) * CDIM + L * 4);
            }
            // compute current tile
            const float* eb = lds_e[p & 1];
            float pa = 0.f, pb = 0.f;
#pragma unroll
            for (int k = 0; k < 16; k += 2) {
                float4 e0 = *(const float4*)&eb[cbase + k * 4];
                float4 e1 = *(const float4*)&eb[cbase + k * 4 + 4];
                pa = fmaf(zr[k].x, e0.x, fmaf(zr[k].y, e0.y,
                     fmaf(zr[k].z, e0.z, fmaf(zr[k].w, e0.w, pa))));
                pb = fmaf(zr[k + 1].x, e1.x, fmaf(zr[k + 1].y, e1.y,
                     fmaf(zr[k + 1].z, e1.z, fmaf(zr[k + 1].w, e1.w, pb))));
            }
            float part = pa + pb;
            // 4-lane group sum -> full dot in all 4 lanes of the group
            part += __shfl_xor(part, 1, 64);
            part += __shfl_xor(part, 2, 64);
            const int j = p * 64 + c;
            const float s = part - 0.5f * lds_en[j];
            if (s > b1) { b1 = s; bj = j; }   // j strictly ascending per thread

            lds_barrier();                    // all reads of lds_e[(p+1)&1] (prev iter) done
            if (p < 15) {
#pragma unroll
                for (int i = 0; i < 16; ++i)
                    *(float4*)&lds_e[(p + 1) & 1][(i * 4 + w) * 272 + wr] = st[i];
            }
            lds_barrier();                    // writes visible before next compute
        }

        // block-wide argmax with smallest-j tie-break (4-lane groups are uniform)
#pragma unroll
        for (int m = 4; m <= 32; m <<= 1) {
            const float o1 = __shfl_xor(b1, m, 64);
            const int   oj = __shfl_xor(bj, m, 64);
            if (o1 > b1 || (o1 == b1 && oj < bj)) { b1 = o1; bj = oj; }
        }
        if (L == 0) { rs[w] = b1; rj[w] = bj; }
        __syncthreads();
        if (tid == 0) {
            float f1 = rs[0]; int fj = rj[0];
#pragma unroll
            for (int v = 1; v < 4; ++v)
                if (rs[v] > f1 || (rs[v] == f1 && rj[v] < fj)) { f1 = rs[v]; fj = rj[v]; }
            idx_ws[n] = fj;
            idx_out[n] = (float)fj;
            atomicAdd(&hist[fj], 1);
        }
    }
}

// ---------------- gather + outputs + loss --------------------------------------
__global__ __launch_bounds__(256) void vq_gather(
    const float* __restrict__ z, const float* __restrict__ emb,
    const int* __restrict__ idx_ws, float* __restrict__ zq,
    float* __restrict__ zq1, double* __restrict__ loss_sum)
{
    __shared__ float es[32 * 129];
    __shared__ int ids[32];
    __shared__ float wred[4];

    const int tid = threadIdx.x, w = tid >> 6, L = tid & 63;
    const int b   = blockIdx.x >> 6;
    const int half = (blockIdx.x >> 5) & 1;
    const int hw0 = (blockIdx.x & 31) << 5;
    const int n0  = (b << 10) + hw0;
    const int c0  = half << 7;

    if (tid < 32) ids[tid] = idx_ws[n0 + tid];
    __syncthreads();

#pragma unroll
    for (int p = 0; p < 4; ++p) {
        int u = p * 256 + tid;
        int r = u >> 5, cq = (u & 31) * 4;
        float4 v = *(const float4*)(emb + (size_t)ids[r] * CDIM + c0 + cq);
        es[r * 129 + cq + 0] = v.x;
        es[r * 129 + cq + 1] = v.y;
        es[r * 129 + cq + 2] = v.z;
        es[r * 129 + cq + 3] = v.w;
    }
    __syncthreads();

    const int row = L & 31, cp = L >> 5;
    const size_t zbase = (size_t)b * (CDIM * HW) + hw0 + row;
    float ls = 0.f;
    for (int rd = 0; rd < 16; ++rd) {
        int cl = rd * 8 + w * 2 + cp;
        size_t off = zbase + (size_t)(c0 + cl) * HW;
        float zv = z[off];
        float e  = es[row * 129 + cl];
        float d  = e - zv;
        zq[off]  = zv + d;     // match ref: zp + (z_q1 - zp)
        zq1[off] = e;
        ls += d * d;
    }

    for (int off = 32; off; off >>= 1) ls += __shfl_down(ls, off, 64);
    if (L == 0) wred[w] = ls;
    __syncthreads();
    if (tid == 0)
        atomicAdd(loss_sum, (double)(wred[0] + wred[1] + wred[2] + wred[3]));
}

// ---------------- finalize: loss scalar + perplexity ---------------------------
__global__ __launch_bounds__(1024) void vq_final(
    const int* __restrict__ hist, const double* __restrict__ loss_sum,
    float* __restrict__ out_loss, float* __restrict__ out_perp)
{
    int tid = threadIdx.x;
    float em = (float)hist[tid] * (1.0f / 32768.0f);
    float term = em * logf(em + 1e-10f);
    for (int off = 32; off; off >>= 1) term += __shfl_down(term, off, 64);
    __shared__ float red[16];
    int lane = tid & 63, wv = tid >> 6;
    if (lane == 0) red[wv] = term;
    __syncthreads();
    if (tid == 0) {
        float s = 0.f;
        for (int i = 0; i < 16; ++i) s += red[i];
        *out_perp = expf(-s);
        *out_loss = (float)(*loss_sum * 1.25 / 8388608.0);
    }
}

extern "C" void kernel_launch(void* const* d_in, const int* in_sizes, int n_in,
                              void* d_out, int out_size, void* d_ws, size_t ws_size,
                              hipStream_t stream) {
    const float* z   = (const float*)d_in[0];
    const float* emb = (const float*)d_in[1];
    float* out = (float*)d_out;
    char*  ws  = (char*)d_ws;

    double* loss_sum    = (double*)(ws + WS_LOSS);
    int*    rcnt        = (int*)(ws + WS_RCNT);
    int*    hist        = (int*)(ws + WS_HIST);
    float*  enorm       = (float*)(ws + WS_ENORM);
    int*    idx_ws      = (int*)(ws + WS_IDX);
    int*    rlist       = (int*)(ws + WS_RLIST);
    float*  s1_ws       = (float*)(ws + WS_S1);
    float*  s2_ws       = (float*)(ws + WS_S2);
    int*    j1_ws       = (int*)(ws + WS_J1);
    unsigned short* ebh = (unsigned short*)(ws + WS_EBH);
    unsigned short* ebl = (unsigned short*)(ws + WS_EBL);
    unsigned short* zbh = (unsigned short*)(ws + WS_ZBH);
    unsigned short* zbl = (unsigned short*)(ws + WS_ZBL);

    hipMemsetAsync(d_ws, 0, 4224, stream);   // loss + rcnt + hist

    vq_prep  <<<528, 256, 0, stream>>>(z, emb, zbh, zbl, ebh, ebl, enorm);
    vq_mfma3 <<<512, 256, 0, stream>>>(zbh, zbl, ebh, ebl, enorm, s1_ws, s2_ws, j1_ws);
    vq_merge <<<128, 256, 0, stream>>>(s1_ws, s2_ws, j1_ws, idx_ws, out + OUT_IDX, hist, rcnt, rlist);
    vq_rescue<<<512, 256, 0, stream>>>(z, emb, enorm, rcnt, rlist, idx_ws, out + OUT_IDX, hist);
    vq_gather<<<2048, 256, 0, stream>>>(z, emb, idx_ws, out + OUT_ZQ, out + OUT_ZQ1, loss_sum);
    vq_final <<<1, 1024, 0, stream>>>(hist, loss_sum, out + OUT_LOSS, out + OUT_PERP);
}

// Round 3
// 238.657 us; speedup vs baseline: 1.5077x; 1.5077x over previous
//
#include <hip/hip_runtime.h>
#include <hip/hip_bf16.h>
#include <math.h>

// Problem constants
#define CDIM 256
#define HW   1024          // 32*32
#define NVEC 32768         // B*H*W
#define NE   1024
#define ZSIZE 8388608      // 32*256*32*32
#define NSPLIT 2           // j-splits (512 codes each)
#define MARGIN 0.05f       // 3-term split-bf16 score error sigma ~1e-4 -> 500 sigma

// Output layout (floats): [loss(1)][z_q(ZSIZE)][perp(1)][idx(NVEC)][z_q1(ZSIZE)]
#define OUT_LOSS 0
#define OUT_ZQ   1
#define OUT_PERP 8388609
#define OUT_IDX  8388610
#define OUT_ZQ1  8421378

// Workspace layout (bytes)
#define WS_LOSS   0
#define WS_RCNT   64
#define WS_HIST   128       // 1024 ints  -> 4224
#define WS_ENORM  4224      // 1024 floats -> 8320
#define WS_IDX    8448      // 32768 ints -> 139520
#define WS_RLIST  139520    // 32768 ints -> 270592
#define WS_S1     270592    // 2*32768 f  -> 532736
#define WS_S2     532736    // -> 794880
#define WS_J1     794880    // -> 1057024
#define WS_EBH    1057024   // 1024*256 bf16 -> 1581312
#define WS_EBL    1581312   // -> 2105600
#define WS_ZBH    2105600   // 32768*256 bf16 -> 18882816
#define WS_ZBL    18882816  // -> 35660032
// Scoreboard for rescue partial argmax: aliases WS_EBH (ebh is dead after
// vq_mfma3; vq_merge zeroes it; vq_rescue atomicMax's it; vq_rfin reads it).
#define WS_SCORE  WS_EBH    // 32768 x u64 = 262144 B (< 524288 B of ebh)

typedef __attribute__((ext_vector_type(8))) short short8;
typedef __attribute__((ext_vector_type(4))) float f32x4;
typedef __attribute__((ext_vector_type(8))) unsigned short ushort8v;

__device__ __forceinline__ unsigned short bf16_rne(float x) {
    union { float f; unsigned u; } v; v.f = x;
    unsigned r = v.u + 0x7FFFu + ((v.u >> 16) & 1u);
    return (unsigned short)(r >> 16);
}
__device__ __forceinline__ float bf16_to_f(unsigned short h) {
    union { unsigned u; float f; } v; v.u = ((unsigned)h) << 16;
    return v.f;
}
// CK-style block_sync_lds: drains LDS ops + barrier, leaves global loads (vmcnt) in flight.
__device__ __forceinline__ void lds_barrier() {
    asm volatile("s_waitcnt lgkmcnt(0)\n\ts_barrier" ::: "memory");
}

// ---------------- fused prep: z transpose+split (blocks 0..511), emb split+norm (512..527)
__global__ __launch_bounds__(256) void vq_prep(
    const float* __restrict__ z, const float* __restrict__ emb,
    unsigned short* __restrict__ zbh, unsigned short* __restrict__ zbl,
    unsigned short* __restrict__ ebh, unsigned short* __restrict__ ebl,
    float* __restrict__ enorm)
{
    const int tid = threadIdx.x, w = tid >> 6, L = tid & 63;
    if (blockIdx.x < 512) {
        __shared__ unsigned short th[64 * 264];
        __shared__ unsigned short tl[64 * 264];
        const int b = blockIdx.x >> 4, hw0 = (blockIdx.x & 15) << 6;
        const float* zp = z + (size_t)b * (CDIM * HW) + hw0;
        for (int i = 0; i < 16; ++i) {
            int k = (i * 4 + w) * 4;
            float f0 = zp[(size_t)(k + 0) * HW + L];
            float f1 = zp[(size_t)(k + 1) * HW + L];
            float f2 = zp[(size_t)(k + 2) * HW + L];
            float f3 = zp[(size_t)(k + 3) * HW + L];
            ushort4 hi = { bf16_rne(f0), bf16_rne(f1), bf16_rne(f2), bf16_rne(f3) };
            ushort4 lo = { bf16_rne(f0 - bf16_to_f(hi.x)), bf16_rne(f1 - bf16_to_f(hi.y)),
                           bf16_rne(f2 - bf16_to_f(hi.z)), bf16_rne(f3 - bf16_to_f(hi.w)) };
            *(ushort4*)&th[L * 264 + k] = hi;
            *(ushort4*)&tl[L * 264 + k] = lo;
        }
        __syncthreads();
#pragma unroll
        for (int it = 0; it < 8; ++it) {
            int row = it * 8 + (tid >> 5);
            int kc = (tid & 31) * 8;
            size_t o = (size_t)(b * 1024 + hw0 + row) * CDIM + kc;
            *(ushort8v*)(zbh + o) = *(ushort8v*)&th[row * 264 + kc];
            *(ushort8v*)(zbl + o) = *(ushort8v*)&tl[row * 264 + kc];
        }
    } else {
        const int cb = (int)(blockIdx.x - 512) * 64;
        for (int p = 0; p < 16; ++p) {
            int code = cb + p * 4 + w;
            float4 v = *(const float4*)(emb + (size_t)code * CDIM + L * 4);
            float s = v.x * v.x + v.y * v.y + v.z * v.z + v.w * v.w;
            for (int off = 32; off; off >>= 1) s += __shfl_down(s, off, 64);
            if (L == 0) enorm[code] = s;
            ushort4 hi = { bf16_rne(v.x), bf16_rne(v.y), bf16_rne(v.z), bf16_rne(v.w) };
            ushort4 lo = { bf16_rne(v.x - bf16_to_f(hi.x)), bf16_rne(v.y - bf16_to_f(hi.y)),
                           bf16_rne(v.z - bf16_to_f(hi.z)), bf16_rne(v.w - bf16_to_f(hi.w)) };
            *(ushort4*)(ebh + (size_t)code * CDIM + L * 4) = hi;
            *(ushort4*)(ebl + (size_t)code * CDIM + L * 4) = lo;
        }
    }
}

// ---------------- 3-term split-bf16 MFMA GEMM, LDS-staged, j-loop inside ----------
__global__ __launch_bounds__(256, 2) void vq_mfma3(
    const unsigned short* __restrict__ zbh, const unsigned short* __restrict__ zbl,
    const unsigned short* __restrict__ ebh, const unsigned short* __restrict__ ebl,
    const float* __restrict__ enorm,
    float* __restrict__ s1_ws, float* __restrict__ s2_ws, int* __restrict__ j1_ws)
{
    __shared__ short albuf[32768];   // 64KB: AL frags, seg(w,mf,kk)=w*16+mf*8+kk, 512 shorts/seg
    __shared__ short bbuf[8192];     // 16KB: B frags, hi: seg=jf, lo: seg=8+jf

    const int tid = threadIdx.x, w = tid >> 6, L = tid & 63;
    const int l15 = L & 15, q = L >> 4;
    const int r16 = tid & 15, ch = (tid >> 4) & 3;
    const int mtile = blockIdx.x & 255, js = blockIdx.x >> 8;
    const int n0 = mtile << 7;
    const int jsbase = js << 9;

    // stage AL (fragment order)
#pragma unroll
    for (int ro = 0; ro < 16; ++ro) {
        const int seg = ro * 4 + w;
        const int sw2 = seg >> 4, smf = (seg >> 3) & 1, skk = seg & 7;
        short8 v = *(const short8*)(zbl + (size_t)(n0 + sw2 * 32 + smf * 16 + r16) * CDIM + skk * 32 + ch * 8);
        *(short8*)(albuf + seg * 512 + L * 8) = v;
    }
    short8 AH[2][8];
#pragma unroll
    for (int mf = 0; mf < 2; ++mf)
#pragma unroll
        for (int kk = 0; kk < 8; ++kk)
            AH[mf][kk] = *(const short8*)(zbh + (size_t)(n0 + w * 32 + mf * 16 + l15) * CDIM + kk * 32 + q * 8);
    __syncthreads();

    float s1[2][4], s2[2][4]; int j1[2][4];
#pragma unroll
    for (int mf = 0; mf < 2; ++mf)
#pragma unroll
        for (int r = 0; r < 4; ++r) { s1[mf][r] = -3.4e38f; s2[mf][r] = -3.4e38f; j1[mf][r] = 0; }

    for (int j0i = 0; j0i < 4; ++j0i) {
        const int j0 = jsbase + j0i * 128;
        f32x4 acc[2][8] = {};
        short8 st[4];
#pragma unroll
        for (int ro = 0; ro < 4; ++ro) {
            const unsigned short* src = (ro >= 2) ? ebl : ebh;
            const int jf = (ro & 1) * 4 + w;
            st[ro] = *(const short8*)(src + (size_t)(j0 + jf * 16 + r16) * CDIM + ch * 8);
        }
#pragma unroll
        for (int kk = 0; kk < 8; ++kk) {
            lds_barrier();
#pragma unroll
            for (int ro = 0; ro < 4; ++ro)
                *(short8*)(bbuf + (ro * 4 + w) * 512 + L * 8) = st[ro];
            if (kk < 7) {
                const int k0n = (kk + 1) * 32;
#pragma unroll
                for (int ro = 0; ro < 4; ++ro) {
                    const unsigned short* src = (ro >= 2) ? ebl : ebh;
                    const int jf = (ro & 1) * 4 + w;
                    st[ro] = *(const short8*)(src + (size_t)(j0 + jf * 16 + r16) * CDIM + k0n + ch * 8);
                }
            }
            lds_barrier();
            short8 AL0 = *(const short8*)(albuf + (w * 16 + kk) * 512 + L * 8);
            short8 AL1 = *(const short8*)(albuf + (w * 16 + 8 + kk) * 512 + L * 8);
#pragma unroll
            for (int jf = 0; jf < 8; ++jf) {
                short8 Bh = *(const short8*)(bbuf + jf * 512 + L * 8);
                short8 Bl = *(const short8*)(bbuf + (8 + jf) * 512 + L * 8);
                acc[0][jf] = __builtin_amdgcn_mfma_f32_16x16x32_bf16(AH[0][kk], Bh, acc[0][jf], 0, 0, 0);
                acc[1][jf] = __builtin_amdgcn_mfma_f32_16x16x32_bf16(AH[1][kk], Bh, acc[1][jf], 0, 0, 0);
                acc[0][jf] = __builtin_amdgcn_mfma_f32_16x16x32_bf16(AH[0][kk], Bl, acc[0][jf], 0, 0, 0);
                acc[1][jf] = __builtin_amdgcn_mfma_f32_16x16x32_bf16(AH[1][kk], Bl, acc[1][jf], 0, 0, 0);
                acc[0][jf] = __builtin_amdgcn_mfma_f32_16x16x32_bf16(AL0, Bh, acc[0][jf], 0, 0, 0);
                acc[1][jf] = __builtin_amdgcn_mfma_f32_16x16x32_bf16(AL1, Bh, acc[1][jf], 0, 0, 0);
            }
        }
#pragma unroll
        for (int jf = 0; jf < 8; ++jf) {
            const int j = j0 + jf * 16 + l15;
            const float hn = 0.5f * enorm[j];
#pragma unroll
            for (int mf = 0; mf < 2; ++mf)
#pragma unroll
                for (int r = 0; r < 4; ++r) {
                    float s = acc[mf][jf][r] - hn;
                    if (s > s1[mf][r]) { s2[mf][r] = s1[mf][r]; s1[mf][r] = s; j1[mf][r] = j; }
                    else if (s > s2[mf][r]) s2[mf][r] = s;
                }
        }
    }

#pragma unroll
    for (int mf = 0; mf < 2; ++mf)
#pragma unroll
        for (int r = 0; r < 4; ++r) {
            float a1 = s1[mf][r], a2 = s2[mf][r]; int aj = j1[mf][r];
            for (int m = 1; m < 16; m <<= 1) {
                float o1 = __shfl_xor(a1, m, 64);
                float o2 = __shfl_xor(a2, m, 64);
                int   oj = __shfl_xor(aj, m, 64);
                if (o1 > a1 || (o1 == a1 && oj < aj)) { a2 = fmaxf(a1, o2); a1 = o1; aj = oj; }
                else a2 = fmaxf(a2, o1);
            }
            if (l15 == 0) {
                int o = js * NVEC + n0 + w * 32 + mf * 16 + q * 4 + r;
                s1_ws[o] = a1; s2_ws[o] = a2; j1_ws[o] = aj;
            }
        }
}

// ---------------- merge 2 splits; hist+idx_out for confident rows; flag rest ----
// Also zeroes the rescue scoreboard (one u64 per possible flagged row).
__global__ __launch_bounds__(256) void vq_merge(
    const float* __restrict__ s1_ws, const float* __restrict__ s2_ws,
    const int* __restrict__ j1_ws, int* __restrict__ idx_ws,
    float* __restrict__ idx_out, int* __restrict__ hist,
    int* __restrict__ rcnt, int* __restrict__ rlist,
    unsigned long long* __restrict__ score)
{
    int n = blockIdx.x * 256 + threadIdx.x;
    score[n] = 0ull;
    float b1 = -3.4e38f, b2 = -3.4e38f; int bj = 0;
#pragma unroll
    for (int s = 0; s < NSPLIT; ++s) {
        float a1 = s1_ws[s * NVEC + n], a2 = s2_ws[s * NVEC + n];
        int aj = j1_ws[s * NVEC + n];
        if (a1 > b1 || (a1 == b1 && aj < bj)) { b2 = fmaxf(b1, a2); b1 = a1; bj = aj; }
        else b2 = fmaxf(b2, a1);
    }
    idx_ws[n] = bj;
    if (b1 - b2 < MARGIN) {
        int p = atomicAdd(rcnt, 1); rlist[p] = n;
    } else {
        idx_out[n] = (float)bj;
        atomicAdd(&hist[bj], 1);
    }
}

// ---------------- exact fp32 rescore of flagged rows ---------------------------
// Post-mortem r0-r2: count is only ~50-60 rows, so rescue time == per-row SERIAL
// latency. r1 (one block/row, 128 dependent iterations) = 69us; r2 (LDS double
// buffer) spilled registers (WRITE_SIZE 100MB) = 152us. v4: CHUNK the codes --
// 16 blocks per row, 64 codes per block, 16 per wave -> only 8 dual-code
// iterations of the proven coalesced inner loop. Partial (score,j) merges via a
// packed u64 atomicMax scoreboard: hi32 = order-preserving float key, lo32 = ~j
// (equal scores -> larger ~j wins == smaller j, matching ref tie-break).
// vq_rfin unpacks after all blocks finish.
__global__ __launch_bounds__(256) void vq_rescue(
    const float* __restrict__ z, const float* __restrict__ emb,
    const float* __restrict__ enorm, const int* __restrict__ rcnt,
    const int* __restrict__ rlist, unsigned long long* __restrict__ score)
{
    __shared__ __align__(16) float zrow[256];
    __shared__ float en_s[64];
    __shared__ float rs[4];
    __shared__ int   rj[4];
    const int tid = threadIdx.x;
    const int wv = tid >> 6, L = tid & 63;
    const int chunk = blockIdx.x & 15;        // 16 chunks of 64 codes
    const int jwave = chunk * 64 + wv * 16;   // this wave's 16 codes
    const int jodd = L >> 5;                  // lo half-wave: even code, hi: odd
    const int rstride = gridDim.x >> 4;
    const int count = *rcnt;

    for (int it = blockIdx.x >> 4; it < count; it += rstride) {
        __syncthreads();   // protect LDS reuse across rows
        const int n = rlist[it];
        zrow[tid] = z[(size_t)(n >> 10) * (CDIM * HW) + (size_t)tid * HW + (n & 1023)];
        if (tid < 64) en_s[tid] = enorm[chunk * 64 + tid];
        __syncthreads();
        const float4 zv = *(const float4*)&zrow[L * 4];

        float b1 = -3.4e38f; int bj = 0x7fffffff;
#pragma unroll
        for (int jo = 0; jo < 16; jo += 2) {
            const int jA = jwave + jo;
            const float4 eA = *(const float4*)(emb + (size_t)jA * CDIM + L * 4);
            const float4 eB = *(const float4*)(emb + (size_t)(jA + 1) * CDIM + L * 4);
            float pA = fmaf(zv.x, eA.x, fmaf(zv.y, eA.y, fmaf(zv.z, eA.z, zv.w * eA.w)));
            float pB = fmaf(zv.x, eB.x, fmaf(zv.y, eB.y, fmaf(zv.z, eB.z, zv.w * eB.w)));
            // dual reduce: fold opposite halves, then 5-step butterfly.
            float tA = pA + __shfl_xor(pA, 32, 64);
            float tB = pB + __shfl_xor(pB, 32, 64);
            float u = (L < 32) ? tA : tB;
            u += __shfl_xor(u, 16, 64);
            u += __shfl_xor(u, 8, 64);
            u += __shfl_xor(u, 4, 64);
            u += __shfl_xor(u, 2, 64);
            u += __shfl_xor(u, 1, 64);
            const int j = jA + jodd;
            const float s = u - 0.5f * en_s[wv * 16 + jo + jodd];
            // ascending j within each half-stream: strict > keeps smallest j
            if (s > b1) { b1 = s; bj = j; }
        }
        // merge the two half-wave streams (even vs odd codes)
        {
            const float o1 = __shfl_xor(b1, 32, 64);
            const int   oj = __shfl_xor(bj, 32, 64);
            if (o1 > b1 || (o1 == b1 && oj < bj)) { b1 = o1; bj = oj; }
        }
        if (L == 0) { rs[wv] = b1; rj[wv] = bj; }
        __syncthreads();
        if (tid == 0) {
            float f1 = rs[0]; int fj = rj[0];
#pragma unroll
            for (int v = 1; v < 4; ++v)
                if (rs[v] > f1 || (rs[v] == f1 && rj[v] < fj)) { f1 = rs[v]; fj = rj[v]; }
            unsigned key = __float_as_uint(f1);
            key = (key & 0x80000000u) ? ~key : (key | 0x80000000u);
            unsigned long long packed = ((unsigned long long)key << 32) | (unsigned)(~fj);
            atomicMax(&score[it], packed);
        }
    }
}

// ---------------- unpack rescue scoreboard -------------------------------------
__global__ __launch_bounds__(256) void vq_rfin(
    const int* __restrict__ rcnt, const int* __restrict__ rlist,
    const unsigned long long* __restrict__ score, int* __restrict__ idx_ws,
    float* __restrict__ idx_out, int* __restrict__ hist)
{
    const int count = *rcnt;
    for (int it = blockIdx.x * 256 + threadIdx.x; it < count; it += gridDim.x * 256) {
        const unsigned long long p = score[it];
        const int fj = (int)(~(unsigned)p) & (NE - 1);
        const int n = rlist[it];
        idx_ws[n] = fj;
        idx_out[n] = (float)fj;
        atomicAdd(&hist[fj], 1);
    }
}

// ---------------- gather + outputs + loss --------------------------------------
__global__ __launch_bounds__(256) void vq_gather(
    const float* __restrict__ z, const float* __restrict__ emb,
    const int* __restrict__ idx_ws, float* __restrict__ zq,
    float* __restrict__ zq1, double* __restrict__ loss_sum)
{
    __shared__ float es[32 * 129];
    __shared__ int ids[32];
    __shared__ float wred[4];

    const int tid = threadIdx.x, w = tid >> 6, L = tid & 63;
    const int b   = blockIdx.x >> 6;
    const int half = (blockIdx.x >> 5) & 1;
    const int hw0 = (blockIdx.x & 31) << 5;
    const int n0  = (b << 10) + hw0;
    const int c0  = half << 7;

    if (tid < 32) ids[tid] = idx_ws[n0 + tid];
    __syncthreads();

#pragma unroll
    for (int p = 0; p < 4; ++p) {
        int u = p * 256 + tid;
        int r = u >> 5, cq = (u & 31) * 4;
        float4 v = *(const float4*)(emb + (size_t)ids[r] * CDIM + c0 + cq);
        es[r * 129 + cq + 0] = v.x;
        es[r * 129 + cq + 1] = v.y;
        es[r * 129 + cq + 2] = v.z;
        es[r * 129 + cq + 3] = v.w;
    }
    __syncthreads();

    const int row = L & 31, cp = L >> 5;
    const size_t zbase = (size_t)b * (CDIM * HW) + hw0 + row;
    float ls = 0.f;
    for (int rd = 0; rd < 16; ++rd) {
        int cl = rd * 8 + w * 2 + cp;
        size_t off = zbase + (size_t)(c0 + cl) * HW;
        float zv = z[off];
        float e  = es[row * 129 + cl];
        float d  = e - zv;
        zq[off]  = zv + d;     // match ref: zp + (z_q1 - zp)
        zq1[off] = e;
        ls += d * d;
    }

    for (int off = 32; off; off >>= 1) ls += __shfl_down(ls, off, 64);
    if (L == 0) wred[w] = ls;
    __syncthreads();
    if (tid == 0)
        atomicAdd(loss_sum, (double)(wred[0] + wred[1] + wred[2] + wred[3]));
}

// ---------------- finalize: loss scalar + perplexity ---------------------------
__global__ __launch_bounds__(1024) void vq_final(
    const int* __restrict__ hist, const double* __restrict__ loss_sum,
    float* __restrict__ out_loss, float* __restrict__ out_perp)
{
    int tid = threadIdx.x;
    float em = (float)hist[tid] * (1.0f / 32768.0f);
    float term = em * logf(em + 1e-10f);
    for (int off = 32; off; off >>= 1) term += __shfl_down(term, off, 64);
    __shared__ float red[16];
    int lane = tid & 63, wv = tid >> 6;
    if (lane == 0) red[wv] = term;
    __syncthreads();
    if (tid == 0) {
        float s = 0.f;
        for (int i = 0; i < 16; ++i) s += red[i];
        *out_perp = expf(-s);
        *out_loss = (float)(*loss_sum * 1.25 / 8388608.0);
    }
}

extern "C" void kernel_launch(void* const* d_in, const int* in_sizes, int n_in,
                              void* d_out, int out_size, void* d_ws, size_t ws_size,
                              hipStream_t stream) {
    const float* z   = (const float*)d_in[0];
    const float* emb = (const float*)d_in[1];
    float* out = (float*)d_out;
    char*  ws  = (char*)d_ws;

    double* loss_sum    = (double*)(ws + WS_LOSS);
    int*    rcnt        = (int*)(ws + WS_RCNT);
    int*    hist        = (int*)(ws + WS_HIST);
    float*  enorm       = (float*)(ws + WS_ENORM);
    int*    idx_ws      = (int*)(ws + WS_IDX);
    int*    rlist       = (int*)(ws + WS_RLIST);
    float*  s1_ws       = (float*)(ws + WS_S1);
    float*  s2_ws       = (float*)(ws + WS_S2);
    int*    j1_ws       = (int*)(ws + WS_J1);
    unsigned short* ebh = (unsigned short*)(ws + WS_EBH);
    unsigned short* ebl = (unsigned short*)(ws + WS_EBL);
    unsigned short* zbh = (unsigned short*)(ws + WS_ZBH);
    unsigned short* zbl = (unsigned short*)(ws + WS_ZBL);
    unsigned long long* score = (unsigned long long*)(ws + WS_SCORE);

    hipMemsetAsync(d_ws, 0, 4224, stream);   // loss + rcnt + hist

    vq_prep  <<<528, 256, 0, stream>>>(z, emb, zbh, zbl, ebh, ebl, enorm);
    vq_mfma3 <<<512, 256, 0, stream>>>(zbh, zbl, ebh, ebl, enorm, s1_ws, s2_ws, j1_ws);
    vq_merge <<<128, 256, 0, stream>>>(s1_ws, s2_ws, j1_ws, idx_ws, out + OUT_IDX, hist, rcnt, rlist, score);
    vq_rescue<<<2048, 256, 0, stream>>>(z, emb, enorm, rcnt, rlist, score);
    vq_rfin  <<<8, 256, 0, stream>>>(rcnt, rlist, score, idx_ws, out + OUT_IDX, hist);
    vq_gather<<<2048, 256, 0, stream>>>(z, emb, idx_ws, out + OUT_ZQ, out + OUT_ZQ1, loss_sum);
    vq_final <<<1, 1024, 0, stream>>>(hist, loss_sum, out + OUT_LOSS, out + OUT_PERP);
}

// Round 4
// 230.539 us; speedup vs baseline: 1.5608x; 1.0352x over previous
//
#include <hip/hip_runtime.h>
#include <hip/hip_bf16.h>
#include <math.h>

// Problem constants
#define CDIM 256
#define HW   1024          // 32*32
#define NVEC 32768         // B*H*W
#define NE   1024
#define ZSIZE 8388608      // 32*256*32*32
#define NSPLIT 2           // j-splits (512 codes each)
// fp16 2-term (zh*eh + zl*eh): dropped term zh*el has pairwise-diff sigma
// ~4.5e-3 -> 0.075 is ~16 sigma. Rescue absorbs the extra flagged rows.
#define MARGIN 0.075f

// Output layout (floats): [loss(1)][z_q(ZSIZE)][perp(1)][idx(NVEC)][z_q1(ZSIZE)]
#define OUT_LOSS 0
#define OUT_ZQ   1
#define OUT_PERP 8388609
#define OUT_IDX  8388610
#define OUT_ZQ1  8421378

// Workspace layout (bytes)
#define WS_LOSS   0
#define WS_RCNT   64
#define WS_HIST   128       // 1024 ints  -> 4224
#define WS_ENORM  4224      // 1024 floats -> 8320
#define WS_IDX    8448      // 32768 ints -> 139520
#define WS_RLIST  139520    // 32768 ints -> 270592
#define WS_S1     270592    // 2*32768 f  -> 532736
#define WS_S2     532736    // -> 794880
#define WS_J1     794880    // -> 1057024
#define WS_EBH    1057024   // 1024*256 fp16 -> 1581312
#define WS_EBL    1581312   // (unused now) -> 2105600
#define WS_ZBH    2105600   // 32768*256 fp16 -> 18882816
#define WS_ZBL    18882816  // -> 35660032
// Scoreboard for rescue partial argmax: aliases WS_EBH+? -- use WS_EBL region
// (never written in fp16-2term scheme; vq_merge zeroes it; rescue atomicMax;
// vq_rfin reads).
#define WS_SCORE  WS_EBL    // 32768 x u64 = 262144 B (< 524288 B region)

typedef __attribute__((ext_vector_type(8))) short short8;
typedef __attribute__((ext_vector_type(4))) float f32x4;
typedef __attribute__((ext_vector_type(8))) unsigned short ushort8v;
typedef __attribute__((ext_vector_type(8))) _Float16 half8;

__device__ __forceinline__ unsigned short f16_rne(float x) {
    _Float16 h = (_Float16)x;
    return __builtin_bit_cast(unsigned short, h);
}
__device__ __forceinline__ float f16_to_f(unsigned short u) {
    return (float)__builtin_bit_cast(_Float16, u);
}
// CK-style block_sync_lds: drains LDS ops + barrier, leaves global loads (vmcnt) in flight.
__device__ __forceinline__ void lds_barrier() {
    asm volatile("s_waitcnt lgkmcnt(0)\n\ts_barrier" ::: "memory");
}

// ---------------- fused prep: z transpose+split (blocks 0..511), emb enc+norm (512..527)
__global__ __launch_bounds__(256) void vq_prep(
    const float* __restrict__ z, const float* __restrict__ emb,
    unsigned short* __restrict__ zbh, unsigned short* __restrict__ zbl,
    unsigned short* __restrict__ ebh, float* __restrict__ enorm)
{
    const int tid = threadIdx.x, w = tid >> 6, L = tid & 63;
    if (blockIdx.x < 512) {
        __shared__ unsigned short th[64 * 264];
        __shared__ unsigned short tl[64 * 264];
        const int b = blockIdx.x >> 4, hw0 = (blockIdx.x & 15) << 6;
        const float* zp = z + (size_t)b * (CDIM * HW) + hw0;
        for (int i = 0; i < 16; ++i) {
            int k = (i * 4 + w) * 4;
            float f0 = zp[(size_t)(k + 0) * HW + L];
            float f1 = zp[(size_t)(k + 1) * HW + L];
            float f2 = zp[(size_t)(k + 2) * HW + L];
            float f3 = zp[(size_t)(k + 3) * HW + L];
            ushort4 hi = { f16_rne(f0), f16_rne(f1), f16_rne(f2), f16_rne(f3) };
            ushort4 lo = { f16_rne(f0 - f16_to_f(hi.x)), f16_rne(f1 - f16_to_f(hi.y)),
                           f16_rne(f2 - f16_to_f(hi.z)), f16_rne(f3 - f16_to_f(hi.w)) };
            *(ushort4*)&th[L * 264 + k] = hi;
            *(ushort4*)&tl[L * 264 + k] = lo;
        }
        __syncthreads();
#pragma unroll
        for (int it = 0; it < 8; ++it) {
            int row = it * 8 + (tid >> 5);
            int kc = (tid & 31) * 8;
            size_t o = (size_t)(b * 1024 + hw0 + row) * CDIM + kc;
            *(ushort8v*)(zbh + o) = *(ushort8v*)&th[row * 264 + kc];
            *(ushort8v*)(zbl + o) = *(ushort8v*)&tl[row * 264 + kc];
        }
    } else {
        const int cb = (int)(blockIdx.x - 512) * 64;
        for (int p = 0; p < 16; ++p) {
            int code = cb + p * 4 + w;
            float4 v = *(const float4*)(emb + (size_t)code * CDIM + L * 4);
            float s = v.x * v.x + v.y * v.y + v.z * v.z + v.w * v.w;
            for (int off = 32; off; off >>= 1) s += __shfl_down(s, off, 64);
            if (L == 0) enorm[code] = s;
            ushort4 hi = { f16_rne(v.x), f16_rne(v.y), f16_rne(v.z), f16_rne(v.w) };
            *(ushort4*)(ebh + (size_t)code * CDIM + L * 4) = hi;
        }
    }
}

// ---------------- 2-term split-fp16 MFMA GEMM, flat 32-tile stream -------------
// score = zh*eh + zl*eh - 0.5||e||^2.  Per tile t = j0i*8+kk: 10 ds_read_b128
// (8 Bh + 2 AL) + 32 MFMA + 2 ds_write_b128, ONE lds_barrier (bbuf double-
// buffered: write tile t+1 into the other half while t is read).
__global__ __launch_bounds__(256, 2) void vq_mfma3(
    const unsigned short* __restrict__ zbh, const unsigned short* __restrict__ zbl,
    const unsigned short* __restrict__ ebh,
    const float* __restrict__ enorm,
    float* __restrict__ s1_ws, float* __restrict__ s2_ws, int* __restrict__ j1_ws)
{
    __shared__ short albuf[32768];   // 64KB: AL frags, seg(w,mf,kk)=w*16+mf*8+kk, 512 shorts/seg
    __shared__ short bbuf[2][4096];  // 2 x 8KB: B hi frags, seg=jf (0..7)

    const int tid = threadIdx.x, w = tid >> 6, L = tid & 63;
    const int l15 = L & 15, q = L >> 4;
    const int r16 = tid & 15, ch = (tid >> 4) & 3;
    const int mtile = blockIdx.x & 255, js = blockIdx.x >> 8;
    const int n0 = mtile << 7;
    const int jsbase = js << 9;

    // stage AL (z-low, fragment order)
#pragma unroll
    for (int ro = 0; ro < 16; ++ro) {
        const int seg = ro * 4 + w;
        const int sw2 = seg >> 4, smf = (seg >> 3) & 1, skk = seg & 7;
        short8 v = *(const short8*)(zbl + (size_t)(n0 + sw2 * 32 + smf * 16 + r16) * CDIM + skk * 32 + ch * 8);
        *(short8*)(albuf + seg * 512 + L * 8) = v;
    }
    half8 AH[2][8];
#pragma unroll
    for (int mf = 0; mf < 2; ++mf)
#pragma unroll
        for (int kk = 0; kk < 8; ++kk)
            AH[mf][kk] = *(const half8*)(zbh + (size_t)(n0 + w * 32 + mf * 16 + l15) * CDIM + kk * 32 + q * 8);
    __syncthreads();

    float s1[2][4], s2[2][4]; int j1[2][4];
#pragma unroll
    for (int mf = 0; mf < 2; ++mf)
#pragma unroll
        for (int r = 0; r < 4; ++r) { s1[mf][r] = -3.4e38f; s2[mf][r] = -3.4e38f; j1[mf][r] = 0; }

    // prologue: tile 0 -> bbuf[0]; prefetch tile 1
    short8 st[2];
#pragma unroll
    for (int ro = 0; ro < 2; ++ro)
        st[ro] = *(const short8*)(ebh + (size_t)(jsbase + (ro * 4 + w) * 16 + r16) * CDIM + ch * 8);
#pragma unroll
    for (int ro = 0; ro < 2; ++ro)
        *(short8*)(bbuf[0] + (ro * 4 + w) * 512 + L * 8) = st[ro];
#pragma unroll
    for (int ro = 0; ro < 2; ++ro)
        st[ro] = *(const short8*)(ebh + (size_t)(jsbase + (ro * 4 + w) * 16 + r16) * CDIM + 32 + ch * 8);
    lds_barrier();

    f32x4 acc[2][8];
#pragma unroll 8
    for (int t = 0; t < 32; ++t) {
        const int kk = t & 7;
        if (kk == 0) {
#pragma unroll
            for (int mf = 0; mf < 2; ++mf)
#pragma unroll
                for (int jf = 0; jf < 8; ++jf)
                    acc[mf][jf] = (f32x4){0.f, 0.f, 0.f, 0.f};
        }
        half8 AL0 = *(const half8*)(albuf + (w * 16 + kk) * 512 + L * 8);
        half8 AL1 = *(const half8*)(albuf + (w * 16 + 8 + kk) * 512 + L * 8);
        const short* bb = bbuf[t & 1];
#pragma unroll
        for (int jf = 0; jf < 8; ++jf) {
            half8 Bh = *(const half8*)(bb + jf * 512 + L * 8);
            acc[0][jf] = __builtin_amdgcn_mfma_f32_16x16x32_f16(AH[0][kk], Bh, acc[0][jf], 0, 0, 0);
            acc[1][jf] = __builtin_amdgcn_mfma_f32_16x16x32_f16(AH[1][kk], Bh, acc[1][jf], 0, 0, 0);
            acc[0][jf] = __builtin_amdgcn_mfma_f32_16x16x32_f16(AL0, Bh, acc[0][jf], 0, 0, 0);
            acc[1][jf] = __builtin_amdgcn_mfma_f32_16x16x32_f16(AL1, Bh, acc[1][jf], 0, 0, 0);
        }
        if (t < 31) {
            // write prefetched tile t+1 into the other buffer (disjoint from
            // current reads; prior-iteration readers of it are behind the
            // previous barrier)
#pragma unroll
            for (int ro = 0; ro < 2; ++ro)
                *(short8*)(bbuf[(t + 1) & 1] + (ro * 4 + w) * 512 + L * 8) = st[ro];
            if (t < 30) {
                const int t2 = t + 2;
                const int j0n = jsbase + (t2 >> 3) * 128;
                const int k0n = (t2 & 7) * 32;
#pragma unroll
                for (int ro = 0; ro < 2; ++ro)
                    st[ro] = *(const short8*)(ebh + (size_t)(j0n + (ro * 4 + w) * 16 + r16) * CDIM + k0n + ch * 8);
            }
            lds_barrier();
        }
        if (kk == 7) {
            const int j0 = jsbase + (t >> 3) * 128;
#pragma unroll
            for (int jf = 0; jf < 8; ++jf) {
                const int j = j0 + jf * 16 + l15;
                const float hn = 0.5f * enorm[j];
#pragma unroll
                for (int mf = 0; mf < 2; ++mf)
#pragma unroll
                    for (int r = 0; r < 4; ++r) {
                        float s = acc[mf][jf][r] - hn;
                        if (s > s1[mf][r]) { s2[mf][r] = s1[mf][r]; s1[mf][r] = s; j1[mf][r] = j; }
                        else if (s > s2[mf][r]) s2[mf][r] = s;
                    }
            }
        }
    }

#pragma unroll
    for (int mf = 0; mf < 2; ++mf)
#pragma unroll
        for (int r = 0; r < 4; ++r) {
            float a1 = s1[mf][r], a2 = s2[mf][r]; int aj = j1[mf][r];
            for (int m = 1; m < 16; m <<= 1) {
                float o1 = __shfl_xor(a1, m, 64);
                float o2 = __shfl_xor(a2, m, 64);
                int   oj = __shfl_xor(aj, m, 64);
                if (o1 > a1 || (o1 == a1 && oj < aj)) { a2 = fmaxf(a1, o2); a1 = o1; aj = oj; }
                else a2 = fmaxf(a2, o1);
            }
            if (l15 == 0) {
                int o = js * NVEC + n0 + w * 32 + mf * 16 + q * 4 + r;
                s1_ws[o] = a1; s2_ws[o] = a2; j1_ws[o] = aj;
            }
        }
}

// ---------------- merge 2 splits; hist+idx_out for confident rows; flag rest ----
// Also zeroes the rescue scoreboard (one u64 per possible flagged row).
__global__ __launch_bounds__(256) void vq_merge(
    const float* __restrict__ s1_ws, const float* __restrict__ s2_ws,
    const int* __restrict__ j1_ws, int* __restrict__ idx_ws,
    float* __restrict__ idx_out, int* __restrict__ hist,
    int* __restrict__ rcnt, int* __restrict__ rlist,
    unsigned long long* __restrict__ score)
{
    int n = blockIdx.x * 256 + threadIdx.x;
    score[n] = 0ull;
    float b1 = -3.4e38f, b2 = -3.4e38f; int bj = 0;
#pragma unroll
    for (int s = 0; s < NSPLIT; ++s) {
        float a1 = s1_ws[s * NVEC + n], a2 = s2_ws[s * NVEC + n];
        int aj = j1_ws[s * NVEC + n];
        if (a1 > b1 || (a1 == b1 && aj < bj)) { b2 = fmaxf(b1, a2); b1 = a1; bj = aj; }
        else b2 = fmaxf(b2, a1);
    }
    idx_ws[n] = bj;
    if (b1 - b2 < MARGIN) {
        int p = atomicAdd(rcnt, 1); rlist[p] = n;
    } else {
        idx_out[n] = (float)bj;
        atomicAdd(&hist[bj], 1);
    }
}

// ---------------- exact fp32 rescore of flagged rows ---------------------------
// 16 blocks per row, 64 codes per block, 16 per wave -> 8 dual-code iterations
// of the coalesced inner loop. Partial (score,j) merges via a packed u64
// atomicMax scoreboard: hi32 = order-preserving float key, lo32 = ~j.
__global__ __launch_bounds__(256) void vq_rescue(
    const float* __restrict__ z, const float* __restrict__ emb,
    const float* __restrict__ enorm, const int* __restrict__ rcnt,
    const int* __restrict__ rlist, unsigned long long* __restrict__ score)
{
    __shared__ __align__(16) float zrow[256];
    __shared__ float en_s[64];
    __shared__ float rs[4];
    __shared__ int   rj[4];
    const int tid = threadIdx.x;
    const int wv = tid >> 6, L = tid & 63;
    const int chunk = blockIdx.x & 15;        // 16 chunks of 64 codes
    const int jwave = chunk * 64 + wv * 16;   // this wave's 16 codes
    const int jodd = L >> 5;                  // lo half-wave: even code, hi: odd
    const int rstride = gridDim.x >> 4;
    const int count = *rcnt;

    for (int it = blockIdx.x >> 4; it < count; it += rstride) {
        __syncthreads();   // protect LDS reuse across rows
        const int n = rlist[it];
        zrow[tid] = z[(size_t)(n >> 10) * (CDIM * HW) + (size_t)tid * HW + (n & 1023)];
        if (tid < 64) en_s[tid] = enorm[chunk * 64 + tid];
        __syncthreads();
        const float4 zv = *(const float4*)&zrow[L * 4];

        float b1 = -3.4e38f; int bj = 0x7fffffff;
#pragma unroll
        for (int jo = 0; jo < 16; jo += 2) {
            const int jA = jwave + jo;
            const float4 eA = *(const float4*)(emb + (size_t)jA * CDIM + L * 4);
            const float4 eB = *(const float4*)(emb + (size_t)(jA + 1) * CDIM + L * 4);
            float pA = fmaf(zv.x, eA.x, fmaf(zv.y, eA.y, fmaf(zv.z, eA.z, zv.w * eA.w)));
            float pB = fmaf(zv.x, eB.x, fmaf(zv.y, eB.y, fmaf(zv.z, eB.z, zv.w * eB.w)));
            // dual reduce: fold opposite halves, then 5-step butterfly.
            float tA = pA + __shfl_xor(pA, 32, 64);
            float tB = pB + __shfl_xor(pB, 32, 64);
            float u = (L < 32) ? tA : tB;
            u += __shfl_xor(u, 16, 64);
            u += __shfl_xor(u, 8, 64);
            u += __shfl_xor(u, 4, 64);
            u += __shfl_xor(u, 2, 64);
            u += __shfl_xor(u, 1, 64);
            const int j = jA + jodd;
            const float s = u - 0.5f * en_s[wv * 16 + jo + jodd];
            // ascending j within each half-stream: strict > keeps smallest j
            if (s > b1) { b1 = s; bj = j; }
        }
        // merge the two half-wave streams (even vs odd codes)
        {
            const float o1 = __shfl_xor(b1, 32, 64);
            const int   oj = __shfl_xor(bj, 32, 64);
            if (o1 > b1 || (o1 == b1 && oj < bj)) { b1 = o1; bj = oj; }
        }
        if (L == 0) { rs[wv] = b1; rj[wv] = bj; }
        __syncthreads();
        if (tid == 0) {
            float f1 = rs[0]; int fj = rj[0];
#pragma unroll
            for (int v = 1; v < 4; ++v)
                if (rs[v] > f1 || (rs[v] == f1 && rj[v] < fj)) { f1 = rs[v]; fj = rj[v]; }
            unsigned key = __float_as_uint(f1);
            key = (key & 0x80000000u) ? ~key : (key | 0x80000000u);
            unsigned long long packed = ((unsigned long long)key << 32) | (unsigned)(~fj);
            atomicMax(&score[it], packed);
        }
    }
}

// ---------------- unpack rescue scoreboard -------------------------------------
__global__ __launch_bounds__(256) void vq_rfin(
    const int* __restrict__ rcnt, const int* __restrict__ rlist,
    const unsigned long long* __restrict__ score, int* __restrict__ idx_ws,
    float* __restrict__ idx_out, int* __restrict__ hist)
{
    const int count = *rcnt;
    for (int it = blockIdx.x * 256 + threadIdx.x; it < count; it += gridDim.x * 256) {
        const unsigned long long p = score[it];
        const int fj = (int)(~(unsigned)p) & (NE - 1);
        const int n = rlist[it];
        idx_ws[n] = fj;
        idx_out[n] = (float)fj;
        atomicAdd(&hist[fj], 1);
    }
}

// ---------------- gather + outputs + loss --------------------------------------
__global__ __launch_bounds__(256) void vq_gather(
    const float* __restrict__ z, const float* __restrict__ emb,
    const int* __restrict__ idx_ws, float* __restrict__ zq,
    float* __restrict__ zq1, double* __restrict__ loss_sum)
{
    __shared__ float es[32 * 129];
    __shared__ int ids[32];
    __shared__ float wred[4];

    const int tid = threadIdx.x, w = tid >> 6, L = tid & 63;
    const int b   = blockIdx.x >> 6;
    const int half = (blockIdx.x >> 5) & 1;
    const int hw0 = (blockIdx.x & 31) << 5;
    const int n0  = (b << 10) + hw0;
    const int c0  = half << 7;

    if (tid < 32) ids[tid] = idx_ws[n0 + tid];
    __syncthreads();

#pragma unroll
    for (int p = 0; p < 4; ++p) {
        int u = p * 256 + tid;
        int r = u >> 5, cq = (u & 31) * 4;
        float4 v = *(const float4*)(emb + (size_t)ids[r] * CDIM + c0 + cq);
        es[r * 129 + cq + 0] = v.x;
        es[r * 129 + cq + 1] = v.y;
        es[r * 129 + cq + 2] = v.z;
        es[r * 129 + cq + 3] = v.w;
    }
    __syncthreads();

    const int row = L & 31, cp = L >> 5;
    const size_t zbase = (size_t)b * (CDIM * HW) + hw0 + row;
    float ls = 0.f;
    for (int rd = 0; rd < 16; ++rd) {
        int cl = rd * 8 + w * 2 + cp;
        size_t off = zbase + (size_t)(c0 + cl) * HW;
        float zv = z[off];
        float e  = es[row * 129 + cl];
        float d  = e - zv;
        zq[off]  = zv + d;     // match ref: zp + (z_q1 - zp)
        zq1[off] = e;
        ls += d * d;
    }

    for (int off = 32; off; off >>= 1) ls += __shfl_down(ls, off, 64);
    if (L == 0) wred[w] = ls;
    __syncthreads();
    if (tid == 0)
        atomicAdd(loss_sum, (double)(wred[0] + wred[1] + wred[2] + wred[3]));
}

// ---------------- finalize: loss scalar + perplexity ---------------------------
__global__ __launch_bounds__(1024) void vq_final(
    const int* __restrict__ hist, const double* __restrict__ loss_sum,
    float* __restrict__ out_loss, float* __restrict__ out_perp)
{
    int tid = threadIdx.x;
    float em = (float)hist[tid] * (1.0f / 32768.0f);
    float term = em * logf(em + 1e-10f);
    for (int off = 32; off; off >>= 1) term += __shfl_down(term, off, 64);
    __shared__ float red[16];
    int lane = tid & 63, wv = tid >> 6;
    if (lane == 0) red[wv] = term;
    __syncthreads();
    if (tid == 0) {
        float s = 0.f;
        for (int i = 0; i < 16; ++i) s += red[i];
        *out_perp = expf(-s);
        *out_loss = (float)(*loss_sum * 1.25 / 8388608.0);
    }
}

extern "C" void kernel_launch(void* const* d_in, const int* in_sizes, int n_in,
                              void* d_out, int out_size, void* d_ws, size_t ws_size,
                              hipStream_t stream) {
    const float* z   = (const float*)d_in[0];
    const float* emb = (const float*)d_in[1];
    float* out = (float*)d_out;
    char*  ws  = (char*)d_ws;

    double* loss_sum    = (double*)(ws + WS_LOSS);
    int*    rcnt        = (int*)(ws + WS_RCNT);
    int*    hist        = (int*)(ws + WS_HIST);
    float*  enorm       = (float*)(ws + WS_ENORM);
    int*    idx_ws      = (int*)(ws + WS_IDX);
    int*    rlist       = (int*)(ws + WS_RLIST);
    float*  s1_ws       = (float*)(ws + WS_S1);
    float*  s2_ws       = (float*)(ws + WS_S2);
    int*    j1_ws       = (int*)(ws + WS_J1);
    unsigned short* ebh = (unsigned short*)(ws + WS_EBH);
    unsigned short* zbh = (unsigned short*)(ws + WS_ZBH);
    unsigned short* zbl = (unsigned short*)(ws + WS_ZBL);
    unsigned long long* score = (unsigned long long*)(ws + WS_SCORE);

    hipMemsetAsync(d_ws, 0, 4224, stream);   // loss + rcnt + hist

    vq_prep  <<<528, 256, 0, stream>>>(z, emb, zbh, zbl, ebh, enorm);
    vq_mfma3 <<<512, 256, 0, stream>>>(zbh, zbl, ebh, enorm, s1_ws, s2_ws, j1_ws);
    vq_merge <<<128, 256, 0, stream>>>(s1_ws, s2_ws, j1_ws, idx_ws, out + OUT_IDX, hist, rcnt, rlist, score);
    vq_rescue<<<2048, 256, 0, stream>>>(z, emb, enorm, rcnt, rlist, score);
    vq_rfin  <<<8, 256, 0, stream>>>(rcnt, rlist, score, idx_ws, out + OUT_IDX, hist);
    vq_gather<<<2048, 256, 0, stream>>>(z, emb, idx_ws, out + OUT_ZQ, out + OUT_ZQ1, loss_sum);
    vq_final <<<1, 1024, 0, stream>>>(hist, loss_sum, out + OUT_LOSS, out + OUT_PERP);
}